// Round 4
// baseline (276.843 us; speedup 1.0000x reference)
//
#include <hip/hip_runtime.h>
#include <math.h>

#define TLEN 7680
#define NB 512
#define NW 8          // waves per block
#define CHUNK 15      // TLEN / NB
#define KMAX 386      // T//DIST + 2
#define GLEN 480      // round(T/64*4)

__device__ __forceinline__ float wsum(float v){
#pragma unroll
  for (int o = 32; o; o >>= 1) v += __shfl_xor(v, o);
  return v;
}
__device__ __forceinline__ float wmaxr(float v){
#pragma unroll
  for (int o = 32; o; o >>= 1) v = fmaxf(v, __shfl_xor(v, o));
  return v;
}
__device__ __forceinline__ float wminr(float v){
#pragma unroll
  for (int o = 32; o; o >>= 1) v = fminf(v, __shfl_xor(v, o));
  return v;
}

__global__ __launch_bounds__(NB, 8)
void bvp_feat_kernel(const float* __restrict__ x, float* __restrict__ out){
  const int tid = threadIdx.x;
  const int lane = tid & 63;
  const int w = tid >> 6;
  const int b = blockIdx.x;

  __shared__ __align__(16) float s_bvp[TLEN];
  __shared__ float s_rri[GLEN];
  __shared__ int   s_pk[KMAX];
  __shared__ float s_cs[256];
  __shared__ float s_sn[256];
  __shared__ float s_r8[8][NW];
  __shared__ float s_q[4][NW];     // separate buffer: avoids WAR race with s_r8
  __shared__ int   s_wtot[NW];
  __shared__ float s_pw[46];
  __shared__ float s_rf[10];

  // twiddle table: cos/sin(2*pi*n/256)
  if (tid < 256){
    float sv, cv;
    sincosf(6.283185307179586f * (float)tid * (1.0f/256.0f), &sv, &cv);
    s_cs[tid] = cv;
    s_sn[tid] = sv;
  }

  // ---- load row into LDS, fused raw moments + min/max ----
  float m1 = 0.f, m2 = 0.f, m3 = 0.f, m4 = 0.f;
  float vmn = INFINITY, vmx = -INFINITY;
  const float4* row4 = (const float4*)(x + (size_t)b * TLEN);
  float4* s4 = (float4*)s_bvp;
  for (int i = tid; i < TLEN/4; i += NB){
    float4 v = row4[i];
    s4[i] = v;
#define ACC1(a) { float _a=(a); m1+=_a; float _q=_a*_a; m2+=_q; m3+=_q*_a; m4+=_q*_q; vmn=fminf(vmn,_a); vmx=fmaxf(vmx,_a); }
    ACC1(v.x) ACC1(v.y) ACC1(v.z) ACC1(v.w)
#undef ACC1
  }
  // combined 6-way block reduction (1 barrier pair)
  m1 = wsum(m1); m2 = wsum(m2); m3 = wsum(m3); m4 = wsum(m4);
  vmn = wminr(vmn); vmx = wmaxr(vmx);
  if (lane == 0){
    s_r8[0][w] = m1; s_r8[1][w] = m2; s_r8[2][w] = m3;
    s_r8[3][w] = m4; s_r8[4][w] = vmn; s_r8[5][w] = vmx;
  }
  __syncthreads();   // also guarantees s_bvp fully populated
  float M1=0.f, M2=0.f, M3=0.f, M4=0.f, MN=INFINITY, MX=-INFINITY;
#pragma unroll
  for (int j = 0; j < NW; ++j){
    M1 += s_r8[0][j]; M2 += s_r8[1][j]; M3 += s_r8[2][j]; M4 += s_r8[3][j];
    MN = fminf(MN, s_r8[4][j]); MX = fmaxf(MX, s_r8[5][j]);
  }
  const float invT = 1.0f / (float)TLEN;
  float mu = M1 * invT;
  float e2 = M2*invT, e3 = M3*invT, e4 = M4*invT;
  float c2 = e2 - mu*mu;
  float c3 = e3 - 3.0f*mu*e2 + 2.0f*mu*mu*mu;
  float c4 = e4 - 4.0f*mu*e3 + 6.0f*mu*mu*e2 - 3.0f*mu*mu*mu*mu;
  float sd = sqrtf(fmaxf(c2, 0.0f));
  float m2c = fmaxf(c2, 1e-30f);
  float skew = c3 / (m2c * sqrtf(m2c));
  float kurt = c4 / (m2c * m2c) - 3.0f;

  // ---- peak detection: branch-free van Herk sliding-window max ----
  // wmax[t] = max over [t-19, t+19] (clipped).  For chunk [base, base+14]:
  //   S1[o]  = max(bvp[A+o .. A+38])   (A = base-19, A+38 = base+19) -> suffix pass
  //   p2(o)  = max(bvp[A+39 .. A+38+o])                              -> rolling prefix
  //   wmax   = max(S1[o], p2)
  const int base = tid * CHUNK;
  const int A = base - 19;
  float S1[CHUNK];
  {
    float run = -INFINITY;
#pragma unroll
    for (int k = 38; k >= 0; --k){
      int idx = A + k;
      float v = (idx >= 0 && idx < TLEN) ? s_bvp[idx] : -INFINITY;
      run = fmaxf(run, v);
      if (k < CHUNK) S1[k] = run;
    }
  }
  unsigned pmask = 0u;
  int pcnt = 0;
  {
    float p2 = -INFINITY;
    float prev = (base > 0) ? s_bvp[base-1] : 0.0f;
    float cur  = s_bvp[base];
#pragma unroll
    for (int o = 0; o < CHUNK; ++o){
      int t = base + o;
      float nxt = (t+1 < TLEN) ? s_bvp[t+1] : 0.0f;
      if (o > 0){
        int idx = t + 19;               // = A + 38 + o
        float v = (idx < TLEN) ? s_bvp[idx] : -INFINITY;
        p2 = fmaxf(p2, v);
      }
      float wm = fmaxf(S1[o], p2);
      if (t >= 1 && t+1 < TLEN && cur > prev && cur > nxt && cur >= wm){
        pmask |= (1u << o); ++pcnt;
      }
      prev = cur; cur = nxt;
    }
  }

  // ---- compact peak indices: wave shuffle scan + 1 barrier ----
  int scan = pcnt;
#pragma unroll
  for (int off = 1; off < 64; off <<= 1){
    int v = __shfl_up(scan, off);
    if (lane >= off) scan += v;
  }
  if (lane == 63) s_wtot[w] = scan;
  __syncthreads();
  int wbase = 0, total = 0;
#pragma unroll
  for (int j = 0; j < NW; ++j){ if (j < w) wbase += s_wtot[j]; total += s_wtot[j]; }
  const int npk = total < KMAX ? total : KMAX;
  {
    int pos = wbase + scan - pcnt;  // exclusive prefix
    unsigned mm = pmask;
    while (mm){
      int o = __ffs(mm) - 1;
      mm &= mm - 1u;
      if (pos < KMAX) s_pk[pos] = base + o;
      ++pos;
    }
  }
  __syncthreads();

  // ---- RR / HRV stats ----
  const int nr = npk > 1 ? npk - 1 : 0;  // valid rr count
  const int ns = npk > 2 ? npk - 2 : 0;  // valid sdf count
  const float INVFS = 1.0f/64.0f;
  float srr=0.f, shr=0.f, ssdf=0.f, ssq=0.f, c50=0.f, samp=0.f;
  float hmx = -INFINITY, hmn = INFINITY;
  for (int i = tid; i < nr; i += NB){
    float rr = (float)(s_pk[i+1]-s_pk[i]) * INVFS;
    srr += rr;
    float hr = 60.0f / fmaxf(rr, 1e-6f);
    shr += hr;
    hmx = fmaxf(hmx, hr); hmn = fminf(hmn, hr);
  }
  for (int i = tid; i < ns; i += NB){
    float r0 = (float)(s_pk[i+1]-s_pk[i]) * INVFS;
    float r1 = (float)(s_pk[i+2]-s_pk[i+1]) * INVFS;
    float d = r1 - r0;
    ssdf += d; ssq += d*d;
    if (fabsf(d) > 0.05f) c50 += 1.0f;
  }
  for (int i = tid; i < npk; i += NB) samp += s_bvp[s_pk[i]];
  // combined 8-way reduction (1 barrier)
  srr = wsum(srr); shr = wsum(shr); ssdf = wsum(ssdf); ssq = wsum(ssq);
  c50 = wsum(c50); samp = wsum(samp); hmx = wmaxr(hmx); hmn = wminr(hmn);
  if (lane == 0){
    s_r8[0][w]=srr; s_r8[1][w]=shr; s_r8[2][w]=ssdf; s_r8[3][w]=ssq;
    s_r8[4][w]=c50; s_r8[5][w]=samp; s_r8[6][w]=hmx; s_r8[7][w]=hmn;
  }
  __syncthreads();
  float Srr=0.f, Shr=0.f, Ssdf=0.f, Ssq=0.f, C50=0.f, Samp=0.f;
  float Hmx=-INFINITY, Hmn=INFINITY;
#pragma unroll
  for (int j = 0; j < NW; ++j){
    Srr += s_r8[0][j]; Shr += s_r8[1][j]; Ssdf += s_r8[2][j]; Ssq += s_r8[3][j];
    C50 += s_r8[4][j]; Samp += s_r8[5][j];
    Hmx = fmaxf(Hmx, s_r8[6][j]); Hmn = fminf(Hmn, s_r8[7][j]);
  }
  const float dnr = fmaxf((float)nr, 1.0f);
  const float dns = fmaxf((float)ns, 1.0f);
  const float dnp = fmaxf((float)npk, 1.0f);
  float mean_rr  = Srr / dnr;
  float mean_hr0 = Shr / dnr;
  float mean_sdf = Ssdf / dns;
  float mean_amp = Samp / dnp;
  float q_rr=0.f, q_hr=0.f, q_sdf=0.f, q_amp=0.f;
  for (int i = tid; i < nr; i += NB){
    float rr = (float)(s_pk[i+1]-s_pk[i]) * INVFS;
    float d = rr - mean_rr; q_rr += d*d;
    float hr = 60.0f / fmaxf(rr, 1e-6f);
    float dh = hr - mean_hr0; q_hr += dh*dh;
  }
  for (int i = tid; i < ns; i += NB){
    float r0 = (float)(s_pk[i+1]-s_pk[i]) * INVFS;
    float r1 = (float)(s_pk[i+2]-s_pk[i+1]) * INVFS;
    float d = (r1 - r0) - mean_sdf; q_sdf += d*d;
  }
  for (int i = tid; i < npk; i += NB){ float d = s_bvp[s_pk[i]] - mean_amp; q_amp += d*d; }
  q_rr = wsum(q_rr); q_hr = wsum(q_hr); q_sdf = wsum(q_sdf); q_amp = wsum(q_amp);
  if (lane == 0){
    s_q[0][w]=q_rr; s_q[1][w]=q_hr; s_q[2][w]=q_sdf; s_q[3][w]=q_amp;
  }
  __syncthreads();
  float Qrr=0.f, Qhr=0.f, Qsdf=0.f, Qamp=0.f;
#pragma unroll
  for (int j = 0; j < NW; ++j){
    Qrr += s_q[0][j]; Qhr += s_q[1][j]; Qsdf += s_q[2][j]; Qamp += s_q[3][j];
  }

  // ---- rise/fall over first min(npk-1, 5) peaks ----
  int limit = npk - 1;
  if (limit > 5) limit = 5;
  if (limit < 0) limit = 0;
  if (tid < 5){
    float rise = 0.f, fall = 0.f;
    if (tid < limit){
      int pk = s_pk[tid];
      float best = INFINITY; int am = 0;
      for (int off = 0; off < 20; ++off){
        int bi = pk - 20 + off;
        float v = (bi >= 0) ? s_bvp[bi] : INFINITY;
        if (v < best){ best = v; am = off; }
      }
      rise = (float)(20 - am) * INVFS;
      best = INFINITY; am = 0;
      for (int off = 0; off < 20; ++off){
        int fi = pk + off;
        float v = (fi < TLEN) ? s_bvp[fi] : INFINITY;
        if (v < best){ best = v; am = off; }
      }
      fall = (float)am * INVFS;
    }
    s_rf[tid] = rise;
    s_rf[5 + tid] = fall;
  }
  __syncthreads();
  float rise_sum = s_rf[0]+s_rf[1]+s_rf[2]+s_rf[3]+s_rf[4];
  float fall_sum = s_rf[5]+s_rf[6]+s_rf[7]+s_rf[8]+s_rf[9];
  const float dlim = fmaxf((float)limit, 1.0f);

  // ---- interp to 4 Hz + Welch band powers (only when cond) ----
  float t_last = (npk >= 1) ? (float)(s_pk[npk-1]-s_pk[0]) * INVFS : 0.0f;
  const bool cond = (npk >= 3) && (t_last * 4.0f > 10.0f);  // uniform per block
  float lf = 0.f, hf = 0.f, lfhf = 0.f;
  if (cond){
    const int p0 = s_pk[0];
    for (int g = tid; g < GLEN; g += NB){
      float t = (float)g * 0.25f;
      // largest j in [0, npk-1] with t_knot[j] <= t  (t_knot[j] = (pk[j]-pk[0])/64, exact)
      int lo = 0, hi = npk - 1;
      while (lo < hi){
        int mid = (lo + hi + 1) >> 1;
        float tk = (float)(s_pk[mid]-p0) * INVFS;
        if (tk <= t) lo = mid; else hi = mid - 1;
      }
      int j = lo;
      float v;
      if (j >= npk-1){
        v = (float)(s_pk[npk-1]-s_pk[npk-2]) * INVFS;  // v_last
      } else {
        float t0 = (float)(s_pk[j]-p0) * INVFS;
        float t1 = (float)(s_pk[j+1]-p0) * INVFS;
        float v0 = (j == 0) ? (float)(s_pk[1]-s_pk[0]) * INVFS
                            : (float)(s_pk[j]-s_pk[j-1]) * INVFS;
        float v1 = (float)(s_pk[j+1]-s_pk[j]) * INVFS;
        v = v0 + (t - t0) * (v1 - v0) / (t1 - t0);
      }
      s_rri[g] = v;
    }
    __syncthreads();
    // segment means (seg0 = rri[0:256], seg1 = rri[128:384]) — combined reduction
    float v0 = (tid < 256) ? s_rri[tid] : 0.f;
    float v1 = (tid < 256) ? s_rri[128 + tid] : 0.f;
    v0 = wsum(v0); v1 = wsum(v1);
    if (lane == 0){ s_q[0][w] = v0; s_q[1][w] = v1; }
    __syncthreads();
    float me0 = 0.f, me1 = 0.f;
#pragma unroll
    for (int j = 0; j < NW; ++j){ me0 += s_q[0][j]; me1 += s_q[1][j]; }
    me0 *= (1.0f/256.0f); me1 *= (1.0f/256.0f);
    // direct DFT at bins 3..25 for both segments: 46 (seg,bin) pairs over 8 waves
    for (int p = w; p < 46; p += NW){
      int k = 3 + (p >> 1);
      int so = (p & 1) * 128;
      float ms = (p & 1) ? me1 : me0;
      float re = 0.f, im = 0.f;
#pragma unroll
      for (int q = 0; q < 4; ++q){
        int n = lane + (q << 6);
        float xv = (s_rri[so + n] - ms) * (0.5f - 0.5f*s_cs[n]);  // Hann
        int ti = (k * n) & 255;
        re += xv * s_cs[ti];
        im -= xv * s_sn[ti];
      }
      re = wsum(re); im = wsum(im);
      if (lane == 0) s_pw[p] = (re*re + im*im) * (2.0f/384.0f);  // *2 (bins 1..127) * scale 1/(4*96)
    }
    __syncthreads();
    const float df = 0.015625f;
    float acc = 0.f;
    for (int k = 3; k <= 9; ++k){
      float pk2 = 0.5f*(s_pw[2*(k-3)] + s_pw[2*(k-3)+1]);  // mean over 2 segments
      acc += (k == 3 || k == 9) ? 0.5f*pk2 : pk2;          // trapezoid weights
    }
    lf = acc * df;
    acc = 0.f;
    for (int k = 10; k <= 25; ++k){
      float pk2 = 0.5f*(s_pw[2*(k-3)] + s_pw[2*(k-3)+1]);
      acc += (k == 10 || k == 25) ? 0.5f*pk2 : pk2;
    }
    hf = acc * df;
    if (hf > 0.f) lfhf = lf / fmaxf(hf, 1e-12f);
  }

  // ---- epilogue ----
  if (tid == 0){
    const bool g1 = npk >= 1, g2 = npk >= 2, g3 = npk >= 3;
    float sdnn  = g2 ? sqrtf(fmaxf(Qrr / dnr, 0.f)) : 0.f;
    float rmssd = g3 ? sqrtf(fmaxf(Ssq / dns, 0.f)) : 0.f;
    float pnn50 = g3 ? (C50 / dns * 100.0f) : 0.f;
    float sdsd  = g3 ? sqrtf(fmaxf(Qsdf / dns, 0.f)) : 0.f;
    float amp_mean = g1 ? mean_amp : 0.f;
    float amp_std  = g1 ? sqrtf(fmaxf(Qamp / dnp, 0.f)) : 0.f;
    float amp_cv = (g1 && amp_mean != 0.f) ? amp_std / amp_mean * 100.0f : 0.f;
    float rise_t = g2 ? rise_sum / dlim : 0.f;
    float fall_t = g2 ? fall_sum / dlim : 0.f;
    float mean_hr = (g2 && mean_rr > 0.f) ? 60.0f / fmaxf(mean_rr, 1e-6f) : 0.f;
    float std_hr = g2 ? sqrtf(fmaxf(Qhr / dnr, 0.f)) : 0.f;
    float hr_rng = g2 ? (Hmx - Hmn) : 0.f;
    float feats[23] = {mu, sd, skew, kurt, MN, MX, MX - MN, sdnn, rmssd, pnn50,
                       sdsd, lf, hf, lfhf, amp_mean, amp_std, amp_cv, rise_t,
                       fall_t, mean_hr, std_hr, hr_rng, (float)npk};
    float* o = out + (size_t)b * 23;
#pragma unroll
    for (int i = 0; i < 23; ++i){
      float v = feats[i];
      o[i] = (v == v && fabsf(v) != INFINITY) ? v : 0.0f;  // nan_to_num
    }
  }
}

extern "C" void kernel_launch(void* const* d_in, const int* in_sizes, int n_in,
                              void* d_out, int out_size, void* d_ws, size_t ws_size,
                              hipStream_t stream){
  const float* x = (const float*)d_in[0];
  float* out = (float*)d_out;
  const int B = in_sizes[0] / TLEN;
  bvp_feat_kernel<<<dim3(B), dim3(NB), 0, stream>>>(x, out);
}

// Round 5
// 141.262 us; speedup vs baseline: 1.9598x; 1.9598x over previous
//
#include <hip/hip_runtime.h>
#include <math.h>

#define TLEN 7680
#define NB 512
#define NW 8          // waves per block
#define CHUNK 15      // TLEN / NB
#define KMAX 386      // T//DIST + 2
#define GLEN 480      // round(T/64*4)

__device__ __forceinline__ float wsum(float v){
#pragma unroll
  for (int o = 32; o; o >>= 1) v += __shfl_xor(v, o);
  return v;
}
__device__ __forceinline__ float wmaxr(float v){
#pragma unroll
  for (int o = 32; o; o >>= 1) v = fmaxf(v, __shfl_xor(v, o));
  return v;
}
__device__ __forceinline__ float wminr(float v){
#pragma unroll
  for (int o = 32; o; o >>= 1) v = fminf(v, __shfl_xor(v, o));
  return v;
}

__global__ __launch_bounds__(NB, 4)
void bvp_feat_kernel(const float* __restrict__ x, float* __restrict__ out){
  const int tid = threadIdx.x;
  const int lane = tid & 63;
  const int w = tid >> 6;
  const int b = blockIdx.x;

  __shared__ __align__(16) float s_bvp[TLEN];
  __shared__ float s_rri[GLEN];
  __shared__ int   s_pk[KMAX];
  __shared__ float s_cs[256];
  __shared__ float s_sn[256];
  __shared__ float s_red[11][NW];
  __shared__ int   s_wtot[NW];
  __shared__ float s_pw[46];
  __shared__ float s_rf[10];
  __shared__ float s_stash[16];   // uniform per-block scalars, LDS-resident

  // twiddle table: cos/sin(2*pi*n/256)
  if (tid < 256){
    float sv, cv;
    sincosf(6.283185307179586f * (float)tid * (1.0f/256.0f), &sv, &cv);
    s_cs[tid] = cv;
    s_sn[tid] = sv;
  }

  // ---- load row into LDS, fused raw moments + min/max ----
  float m1 = 0.f, m2 = 0.f, m3 = 0.f, m4 = 0.f;
  float vmn = INFINITY, vmx = -INFINITY;
  const float4* row4 = (const float4*)(x + (size_t)b * TLEN);
  float4* s4 = (float4*)s_bvp;
  for (int i = tid; i < TLEN/4; i += NB){
    float4 v = row4[i];
    s4[i] = v;
#define ACC1(a) { float _a=(a); m1+=_a; float _q=_a*_a; m2+=_q; m3+=_q*_a; m4+=_q*_q; vmn=fminf(vmn,_a); vmx=fmaxf(vmx,_a); }
    ACC1(v.x) ACC1(v.y) ACC1(v.z) ACC1(v.w)
#undef ACC1
  }
  m1 = wsum(m1); m2 = wsum(m2); m3 = wsum(m3); m4 = wsum(m4);
  vmn = wminr(vmn); vmx = wmaxr(vmx);
  if (lane == 0){
    s_red[0][w] = m1; s_red[1][w] = m2; s_red[2][w] = m3;
    s_red[3][w] = m4; s_red[4][w] = vmn; s_red[5][w] = vmx;
  }
  __syncthreads();   // [A] also guarantees s_bvp fully populated

  // moments finalized by tid 64 only -> LDS stash (frees regs on all threads)
  if (tid == 64){
    float M1=0.f, M2=0.f, M3=0.f, M4=0.f, MN=INFINITY, MX=-INFINITY;
#pragma unroll
    for (int j = 0; j < NW; ++j){
      M1 += s_red[0][j]; M2 += s_red[1][j]; M3 += s_red[2][j]; M4 += s_red[3][j];
      MN = fminf(MN, s_red[4][j]); MX = fmaxf(MX, s_red[5][j]);
    }
    const float invT = 1.0f / (float)TLEN;
    float mu = M1 * invT;
    float e2 = M2*invT, e3 = M3*invT, e4 = M4*invT;
    float c2 = e2 - mu*mu;
    float c3 = e3 - 3.0f*mu*e2 + 2.0f*mu*mu*mu;
    float c4 = e4 - 4.0f*mu*e3 + 6.0f*mu*mu*e2 - 3.0f*mu*mu*mu*mu;
    float m2c = fmaxf(c2, 1e-30f);
    s_stash[0] = mu;
    s_stash[1] = sqrtf(fmaxf(c2, 0.0f));
    s_stash[2] = c3 / (m2c * sqrtf(m2c));
    s_stash[3] = c4 / (m2c * m2c) - 3.0f;
    s_stash[4] = MN;
    s_stash[5] = MX;
  }

  // ---- peak detection: branch-free van Herk sliding-window max ----
  const int base = tid * CHUNK;
  const int A = base - 19;
  float S1[CHUNK];
  {
    float run = -INFINITY;
#pragma unroll
    for (int k = 38; k >= 0; --k){
      int idx = A + k;
      float v = (idx >= 0 && idx < TLEN) ? s_bvp[idx] : -INFINITY;
      run = fmaxf(run, v);
      if (k < CHUNK) S1[k] = run;
    }
  }
  unsigned pmask = 0u;
  int pcnt = 0;
  {
    float p2 = -INFINITY;
    float prev = (base > 0) ? s_bvp[base-1] : 0.0f;
    float cur  = s_bvp[base];
#pragma unroll
    for (int o = 0; o < CHUNK; ++o){
      int t = base + o;
      float nxt = (t+1 < TLEN) ? s_bvp[t+1] : 0.0f;
      if (o > 0){
        int idx = t + 19;               // = A + 38 + o
        float v = (idx < TLEN) ? s_bvp[idx] : -INFINITY;
        p2 = fmaxf(p2, v);
      }
      float wm = fmaxf(S1[o], p2);
      if (t >= 1 && t+1 < TLEN && cur > prev && cur > nxt && cur >= wm){
        pmask |= (1u << o); ++pcnt;
      }
      prev = cur; cur = nxt;
    }
  }

  // ---- compact peak indices: wave shuffle scan + 1 barrier ----
  int scan = pcnt;
#pragma unroll
  for (int off = 1; off < 64; off <<= 1){
    int v = __shfl_up(scan, off);
    if (lane >= off) scan += v;
  }
  if (lane == 63) s_wtot[w] = scan;
  __syncthreads();   // [B]
  int wbase = 0, total = 0;
#pragma unroll
  for (int j = 0; j < NW; ++j){ if (j < w) wbase += s_wtot[j]; total += s_wtot[j]; }
  const int npk = total < KMAX ? total : KMAX;
  {
    int pos = wbase + scan - pcnt;  // exclusive prefix
    unsigned mm = pmask;
    while (mm){
      int o = __ffs(mm) - 1;
      mm &= mm - 1u;
      if (pos < KMAX) s_pk[pos] = base + o;
      ++pos;
    }
  }
  __syncthreads();   // [C]

  // ---- rise/fall over first min(npk-1, 5) peaks (tid<5; merged barrier) ----
  const float INVFS = 1.0f/64.0f;
  if (tid < 5){
    int limit = npk - 1;
    if (limit > 5) limit = 5;
    float rise = 0.f, fall = 0.f;
    if (tid < limit){
      int pk = s_pk[tid];
      float best = INFINITY; int am = 0;
      for (int off = 0; off < 20; ++off){
        int bi = pk - 20 + off;
        float v = (bi >= 0) ? s_bvp[bi] : INFINITY;
        if (v < best){ best = v; am = off; }
      }
      rise = (float)(20 - am) * INVFS;
      best = INFINITY; am = 0;
      for (int off = 0; off < 20; ++off){
        int fi = pk + off;
        float v = (fi < TLEN) ? s_bvp[fi] : INFINITY;
        if (v < best){ best = v; am = off; }
      }
      fall = (float)am * INVFS;
    }
    s_rf[tid] = rise;
    s_rf[5 + tid] = fall;
  }

  // ---- RR / HRV stats: single pass, raw moments ----
  const int nr = npk > 1 ? npk - 1 : 0;
  const int ns = npk > 2 ? npk - 2 : 0;
  {
    float srr=0.f, srr2=0.f, shr=0.f, shr2=0.f;
    float ssdf=0.f, ssdf2=0.f, c50=0.f, samp=0.f, samp2=0.f;
    float hmx = -INFINITY, hmn = INFINITY;
    for (int i = tid; i < nr; i += NB){
      float rr = (float)(s_pk[i+1]-s_pk[i]) * INVFS;
      srr += rr; srr2 += rr*rr;
      float hr = 60.0f / fmaxf(rr, 1e-6f);
      shr += hr; shr2 += hr*hr;
      hmx = fmaxf(hmx, hr); hmn = fminf(hmn, hr);
    }
    for (int i = tid; i < ns; i += NB){
      float r0 = (float)(s_pk[i+1]-s_pk[i]) * INVFS;
      float r1 = (float)(s_pk[i+2]-s_pk[i+1]) * INVFS;
      float d = r1 - r0;
      ssdf += d; ssdf2 += d*d;
      if (fabsf(d) > 0.05f) c50 += 1.0f;
    }
    for (int i = tid; i < npk; i += NB){
      float a = s_bvp[s_pk[i]];
      samp += a; samp2 += a*a;
    }
    srr = wsum(srr); srr2 = wsum(srr2); shr = wsum(shr); shr2 = wsum(shr2);
    ssdf = wsum(ssdf); ssdf2 = wsum(ssdf2); c50 = wsum(c50);
    samp = wsum(samp); samp2 = wsum(samp2);
    hmx = wmaxr(hmx); hmn = wminr(hmn);
    if (lane == 0){
      s_red[0][w]=srr; s_red[1][w]=srr2; s_red[2][w]=shr; s_red[3][w]=shr2;
      s_red[4][w]=ssdf; s_red[5][w]=ssdf2; s_red[6][w]=c50;
      s_red[7][w]=samp; s_red[8][w]=samp2; s_red[9][w]=hmx; s_red[10][w]=hmn;
    }
  }
  __syncthreads();   // [D]

  // HRV finals by tid 128 only -> stash
  if (tid == 128){
    float Srr=0.f, Srr2=0.f, Shr=0.f, Shr2=0.f, Ssdf=0.f, Ssdf2=0.f;
    float C50=0.f, Samp=0.f, Samp2=0.f, Hmx=-INFINITY, Hmn=INFINITY;
#pragma unroll
    for (int j = 0; j < NW; ++j){
      Srr += s_red[0][j]; Srr2 += s_red[1][j]; Shr += s_red[2][j]; Shr2 += s_red[3][j];
      Ssdf += s_red[4][j]; Ssdf2 += s_red[5][j]; C50 += s_red[6][j];
      Samp += s_red[7][j]; Samp2 += s_red[8][j];
      Hmx = fmaxf(Hmx, s_red[9][j]); Hmn = fminf(Hmn, s_red[10][j]);
    }
    const bool g1 = npk >= 1, g2 = npk >= 2, g3 = npk >= 3;
    const float dnr = fmaxf((float)nr, 1.0f);
    const float dns = fmaxf((float)ns, 1.0f);
    const float dnp = fmaxf((float)npk, 1.0f);
    float mean_rr = Srr / dnr;
    float msdf = Ssdf / dns;
    float mhr0 = Shr / dnr;
    float amp_mean = Samp / dnp;
    float amp_std = sqrtf(fmaxf(Samp2/dnp - amp_mean*amp_mean, 0.f));
    s_stash[6]  = g2 ? sqrtf(fmaxf(Srr2/dnr - mean_rr*mean_rr, 0.f)) : 0.f;  // sdnn
    s_stash[7]  = g3 ? sqrtf(fmaxf(Ssdf2/dns, 0.f)) : 0.f;                   // rmssd
    s_stash[8]  = g3 ? (C50 / dns * 100.0f) : 0.f;                           // pnn50
    s_stash[9]  = g3 ? sqrtf(fmaxf(Ssdf2/dns - msdf*msdf, 0.f)) : 0.f;       // sdsd
    s_stash[10] = g1 ? amp_mean : 0.f;
    s_stash[11] = g1 ? amp_std : 0.f;
    s_stash[12] = (g1 && amp_mean != 0.f) ? amp_std / amp_mean * 100.0f : 0.f;
    s_stash[13] = (g2 && mean_rr > 0.f) ? 60.0f / fmaxf(mean_rr, 1e-6f) : 0.f; // mean_hr
    s_stash[14] = g2 ? sqrtf(fmaxf(Shr2/dnr - mhr0*mhr0, 0.f)) : 0.f;        // std_hr
    s_stash[15] = g2 ? (Hmx - Hmn) : 0.f;                                    // hr_rng
  }

  // ---- interp to 4 Hz + Welch band powers (only when cond) ----
  float t_last = (npk >= 1) ? (float)(s_pk[npk-1]-s_pk[0]) * INVFS : 0.0f;
  const bool cond = (npk >= 3) && (t_last * 4.0f > 10.0f);  // uniform per block
  if (cond){
    const int p0 = s_pk[0];
    for (int g = tid; g < GLEN; g += NB){
      float t = (float)g * 0.25f;
      int lo = 0, hi = npk - 1;
      while (lo < hi){
        int mid = (lo + hi + 1) >> 1;
        float tk = (float)(s_pk[mid]-p0) * INVFS;
        if (tk <= t) lo = mid; else hi = mid - 1;
      }
      int j = lo;
      float v;
      if (j >= npk-1){
        v = (float)(s_pk[npk-1]-s_pk[npk-2]) * INVFS;  // v_last
      } else {
        float t0 = (float)(s_pk[j]-p0) * INVFS;
        float t1 = (float)(s_pk[j+1]-p0) * INVFS;
        float v0 = (j == 0) ? (float)(s_pk[1]-s_pk[0]) * INVFS
                            : (float)(s_pk[j]-s_pk[j-1]) * INVFS;
        float v1 = (float)(s_pk[j+1]-s_pk[j]) * INVFS;
        v = v0 + (t - t0) * (v1 - v0) / (t1 - t0);
      }
      s_rri[g] = v;
    }
    __syncthreads();   // [E]
    // segment means (seg0 = rri[0:256], seg1 = rri[128:384])
    float v0 = (tid < 256) ? s_rri[tid] : 0.f;
    float v1 = (tid < 256) ? s_rri[128 + tid] : 0.f;
    v0 = wsum(v0); v1 = wsum(v1);
    if (lane == 0){ s_red[0][w] = v0; s_red[1][w] = v1; }
    __syncthreads();   // [F]
    float me0 = 0.f, me1 = 0.f;
#pragma unroll
    for (int j = 0; j < NW; ++j){ me0 += s_red[0][j]; me1 += s_red[1][j]; }
    me0 *= (1.0f/256.0f); me1 *= (1.0f/256.0f);
    // direct DFT at bins 3..25 for both segments: 46 (seg,bin) pairs over 8 waves
    for (int p = w; p < 46; p += NW){
      int k = 3 + (p >> 1);
      int so = (p & 1) * 128;
      float ms = (p & 1) ? me1 : me0;
      float re = 0.f, im = 0.f;
#pragma unroll
      for (int q = 0; q < 4; ++q){
        int n = lane + (q << 6);
        float xv = (s_rri[so + n] - ms) * (0.5f - 0.5f*s_cs[n]);  // Hann
        int ti = (k * n) & 255;
        re += xv * s_cs[ti];
        im -= xv * s_sn[ti];
      }
      re = wsum(re); im = wsum(im);
      if (lane == 0) s_pw[p] = (re*re + im*im) * (2.0f/384.0f);  // *2 * 1/(4*96)
    }
  }
  __syncthreads();   // [G] unconditional: covers stash/s_rf/s_pw -> epilogue

  // ---- epilogue ----
  if (tid == 0){
    const bool g2 = npk >= 2, g3 = npk >= 3;
    int limit = npk - 1;
    if (limit > 5) limit = 5;
    if (limit < 0) limit = 0;
    const float dlim = fmaxf((float)limit, 1.0f);
    float rise_t = g2 ? (s_rf[0]+s_rf[1]+s_rf[2]+s_rf[3]+s_rf[4]) / dlim : 0.f;
    float fall_t = g2 ? (s_rf[5]+s_rf[6]+s_rf[7]+s_rf[8]+s_rf[9]) / dlim : 0.f;
    float lf = 0.f, hf = 0.f, lfhf = 0.f;
    if (cond){
      const float df = 0.015625f;
      float acc = 0.f;
      for (int k = 3; k <= 9; ++k){
        float pk2 = 0.5f*(s_pw[2*(k-3)] + s_pw[2*(k-3)+1]);
        acc += (k == 3 || k == 9) ? 0.5f*pk2 : pk2;
      }
      lf = acc * df;
      acc = 0.f;
      for (int k = 10; k <= 25; ++k){
        float pk2 = 0.5f*(s_pw[2*(k-3)] + s_pw[2*(k-3)+1]);
        acc += (k == 10 || k == 25) ? 0.5f*pk2 : pk2;
      }
      hf = acc * df;
      if (hf > 0.f) lfhf = lf / fmaxf(hf, 1e-12f);
    }
    float feats[23] = {s_stash[0], s_stash[1], s_stash[2], s_stash[3],
                       s_stash[4], s_stash[5], s_stash[5]-s_stash[4],
                       s_stash[6], s_stash[7], s_stash[8], s_stash[9],
                       lf, hf, lfhf,
                       s_stash[10], s_stash[11], s_stash[12],
                       rise_t, fall_t,
                       s_stash[13], s_stash[14], s_stash[15], (float)npk};
    float* o = out + (size_t)b * 23;
#pragma unroll
    for (int i = 0; i < 23; ++i){
      float v = feats[i];
      o[i] = (v == v && fabsf(v) != INFINITY) ? v : 0.0f;  // nan_to_num
    }
  }
}

extern "C" void kernel_launch(void* const* d_in, const int* in_sizes, int n_in,
                              void* d_out, int out_size, void* d_ws, size_t ws_size,
                              hipStream_t stream){
  const float* x = (const float*)d_in[0];
  float* out = (float*)d_out;
  const int B = in_sizes[0] / TLEN;
  bvp_feat_kernel<<<dim3(B), dim3(NB), 0, stream>>>(x, out);
}

// Round 6
// 116.091 us; speedup vs baseline: 2.3847x; 1.2168x over previous
//
#include <hip/hip_runtime.h>
#include <math.h>

#define TLEN 7680
#define NB 384
#define NW 6          // waves per block
#define CHUNK 20      // TLEN / NB ; CHUNK > DIST-1=19 => window spans <=1 neighbor chunk
#define KMAX 386      // T//DIST + 2
#define GLEN 480      // round(T/64*4)

__device__ __forceinline__ float wsum(float v){
#pragma unroll
  for (int o = 32; o; o >>= 1) v += __shfl_xor(v, o);
  return v;
}
__device__ __forceinline__ float wmaxr(float v){
#pragma unroll
  for (int o = 32; o; o >>= 1) v = fmaxf(v, __shfl_xor(v, o));
  return v;
}
__device__ __forceinline__ float wminr(float v){
#pragma unroll
  for (int o = 32; o; o >>= 1) v = fminf(v, __shfl_xor(v, o));
  return v;
}

__global__ __launch_bounds__(NB, 4)
void bvp_feat_kernel(const float* __restrict__ x, float* __restrict__ out){
  const int tid = threadIdx.x;
  const int lane = tid & 63;
  const int w = tid >> 6;
  const int b = blockIdx.x;

  __shared__ __align__(16) float s_bvp[TLEN];
  __shared__ float s_rri[GLEN];
  __shared__ int   s_pk[KMAX];
  __shared__ float s_cs[256];
  __shared__ float s_sn[256];
  __shared__ float s_red[11][NW];
  __shared__ int   s_wtot[NW];
  __shared__ float s_pw[46];
  __shared__ float s_rf[10];
  __shared__ float s_stash[16];   // uniform per-block scalars, LDS-resident

  // twiddle table: cos/sin(2*pi*n/256)
  if (tid < 256){
    float sv, cv;
    __sincosf(6.283185307179586f * (float)tid * (1.0f/256.0f), &sv, &cv);
    s_cs[tid] = cv;
    s_sn[tid] = sv;
  }

  // ---- load row into LDS, fused raw moments + min/max ----
  float m1 = 0.f, m2 = 0.f, m3 = 0.f, m4 = 0.f;
  float vmn = INFINITY, vmx = -INFINITY;
  const float4* row4 = (const float4*)(x + (size_t)b * TLEN);
  float4* s4 = (float4*)s_bvp;
#pragma unroll
  for (int q = 0; q < TLEN/4/NB; ++q){
    int i = tid + q * NB;
    float4 v = row4[i];
    s4[i] = v;
#define ACC1(a) { float _a=(a); m1+=_a; float _q=_a*_a; m2+=_q; m3+=_q*_a; m4+=_q*_q; vmn=fminf(vmn,_a); vmx=fmaxf(vmx,_a); }
    ACC1(v.x) ACC1(v.y) ACC1(v.z) ACC1(v.w)
#undef ACC1
  }
  m1 = wsum(m1); m2 = wsum(m2); m3 = wsum(m3); m4 = wsum(m4);
  vmn = wminr(vmn); vmx = wmaxr(vmx);
  if (lane == 0){
    s_red[0][w] = m1; s_red[1][w] = m2; s_red[2][w] = m3;
    s_red[3][w] = m4; s_red[4][w] = vmn; s_red[5][w] = vmx;
  }
  __syncthreads();   // [A] also guarantees s_bvp fully populated

  // moments finalized by tid 64 only -> LDS stash
  if (tid == 64){
    float M1=0.f, M2=0.f, M3=0.f, M4=0.f, MN=INFINITY, MX=-INFINITY;
#pragma unroll
    for (int j = 0; j < NW; ++j){
      M1 += s_red[0][j]; M2 += s_red[1][j]; M3 += s_red[2][j]; M4 += s_red[3][j];
      MN = fminf(MN, s_red[4][j]); MX = fmaxf(MX, s_red[5][j]);
    }
    const float invT = 1.0f / (float)TLEN;
    float mu = M1 * invT;
    float e2 = M2*invT, e3 = M3*invT, e4 = M4*invT;
    float c2 = e2 - mu*mu;
    float c3 = e3 - 3.0f*mu*e2 + 2.0f*mu*mu*mu;
    float c4 = e4 - 4.0f*mu*e3 + 6.0f*mu*mu*e2 - 3.0f*mu*mu*mu*mu;
    float m2c = fmaxf(c2, 1e-30f);
    s_stash[0] = mu;
    s_stash[1] = sqrtf(fmaxf(c2, 0.0f));
    s_stash[2] = c3 / (m2c * sqrtf(m2c));
    s_stash[3] = c4 / (m2c * m2c) - 3.0f;
    s_stash[4] = MN;
    s_stash[5] = MX;
  }

  // ---- peak detection: chunk-local window max (CHUNK=20 > DIST-1) ----
  // window [t-19, t+19] for t=base+o always contains the whole own chunk,
  // plus suffix of prev chunk (prev[o+1..19]) and prefix of next (next[0..o-1]).
  const int base = tid * CHUNK;
  const bool has_prev = (tid > 0);
  const bool has_next = (tid < NB-1);
  float v[CHUNK];
  {
    const float4* sb4 = (const float4*)(s_bvp + base);   // 16B aligned (base%4==0)
#pragma unroll
    for (int q = 0; q < 5; ++q){
      float4 t4 = sb4[q];
      v[4*q+0]=t4.x; v[4*q+1]=t4.y; v[4*q+2]=t4.z; v[4*q+3]=t4.w;
    }
  }
  float M = v[0];
#pragma unroll
  for (int j = 1; j < CHUNK; ++j) M = fmaxf(M, v[j]);

  unsigned cmask = 0u;
  {
    // upward pass: rolling prefix-max of next chunk + local-max + own-max tests
    float pn = -INFINITY;
    float next0 = 0.0f;
    float4 nq;
    const float4* nb4 = (const float4*)(s_bvp + (has_next ? base + CHUNK : 0));
    float prevs0 = has_prev ? s_bvp[base-1] : 0.0f;
#pragma unroll
    for (int o = 0; o < CHUNK; ++o){
      if (o >= 1){
        const int j = o - 1;
        if ((j & 3) == 0) nq = nb4[j >> 2];
        float nv = ((j&3)==0) ? nq.x : ((j&3)==1) ? nq.y : ((j&3)==2) ? nq.z : nq.w;
        if (o == 1) next0 = nv;
        if (has_next) pn = fmaxf(pn, nv);
      }
      float cur = v[o];
      float prevs = (o == 0) ? prevs0 : v[o-1];
      float nxts  = (o == CHUNK-1) ? next0 : v[o+1];
      bool edge_ok = (base + o >= 1) && (base + o + 1 < TLEN);
      if (edge_ok && cur > prevs && cur > nxts && cur >= M && cur >= pn)
        cmask |= (1u << o);
    }
  }
  unsigned pmask = 0u;
  int pcnt = 0;
  {
    // downward pass: rolling suffix-max of prev chunk
    float sp = -INFINITY;
    float4 pq;
    const float4* pb4 = (const float4*)(s_bvp + (has_prev ? base - CHUNK : 0));
#pragma unroll
    for (int o = CHUNK-1; o >= 0; --o){
      if (((cmask >> o) & 1u) && (v[o] >= sp)){ pmask |= (1u << o); ++pcnt; }
      if (o > 0){
        if ((o & 3) == 3 || o == CHUNK-1) pq = pb4[o >> 2];
        float pv = ((o&3)==0) ? pq.x : ((o&3)==1) ? pq.y : ((o&3)==2) ? pq.z : pq.w;
        if (has_prev) sp = fmaxf(sp, pv);
      }
    }
  }

  // ---- compact peak indices: wave shuffle scan + 1 barrier ----
  int scan = pcnt;
#pragma unroll
  for (int off = 1; off < 64; off <<= 1){
    int t = __shfl_up(scan, off);
    if (lane >= off) scan += t;
  }
  if (lane == 63) s_wtot[w] = scan;
  __syncthreads();   // [B]
  int wbase = 0, total = 0;
#pragma unroll
  for (int j = 0; j < NW; ++j){ if (j < w) wbase += s_wtot[j]; total += s_wtot[j]; }
  const int npk = total < KMAX ? total : KMAX;
  {
    int pos = wbase + scan - pcnt;  // exclusive prefix
    unsigned mm = pmask;
    while (mm){
      int o = __ffs(mm) - 1;
      mm &= mm - 1u;
      if (pos < KMAX) s_pk[pos] = base + o;
      ++pos;
    }
  }
  __syncthreads();   // [C]

  // ---- rise/fall over first min(npk-1, 5) peaks ----
  const float INVFS = 1.0f/64.0f;
  if (tid < 5){
    int limit = npk - 1;
    if (limit > 5) limit = 5;
    float rise = 0.f, fall = 0.f;
    if (tid < limit){
      int pk = s_pk[tid];
      float best = INFINITY; int am = 0;
      for (int off = 0; off < 20; ++off){
        int bi = pk - 20 + off;
        float vv = (bi >= 0) ? s_bvp[bi] : INFINITY;
        if (vv < best){ best = vv; am = off; }
      }
      rise = (float)(20 - am) * INVFS;
      best = INFINITY; am = 0;
      for (int off = 0; off < 20; ++off){
        int fi = pk + off;
        float vv = (fi < TLEN) ? s_bvp[fi] : INFINITY;
        if (vv < best){ best = vv; am = off; }
      }
      fall = (float)am * INVFS;
    }
    s_rf[tid] = rise;
    s_rf[5 + tid] = fall;
  }

  // ---- RR / HRV stats: single pass, raw moments ----
  const int nr = npk > 1 ? npk - 1 : 0;
  const int ns = npk > 2 ? npk - 2 : 0;
  {
    float srr=0.f, srr2=0.f, shr=0.f, shr2=0.f;
    float ssdf=0.f, ssdf2=0.f, c50=0.f, samp=0.f, samp2=0.f;
    float hmx = -INFINITY, hmn = INFINITY;
    for (int i = tid; i < nr; i += NB){
      float rr = (float)(s_pk[i+1]-s_pk[i]) * INVFS;
      srr += rr; srr2 += rr*rr;
      float hr = 60.0f / fmaxf(rr, 1e-6f);
      shr += hr; shr2 += hr*hr;
      hmx = fmaxf(hmx, hr); hmn = fminf(hmn, hr);
    }
    for (int i = tid; i < ns; i += NB){
      float r0 = (float)(s_pk[i+1]-s_pk[i]) * INVFS;
      float r1 = (float)(s_pk[i+2]-s_pk[i+1]) * INVFS;
      float d = r1 - r0;
      ssdf += d; ssdf2 += d*d;
      if (fabsf(d) > 0.05f) c50 += 1.0f;
    }
    for (int i = tid; i < npk; i += NB){
      float a = s_bvp[s_pk[i]];
      samp += a; samp2 += a*a;
    }
    srr = wsum(srr); srr2 = wsum(srr2); shr = wsum(shr); shr2 = wsum(shr2);
    ssdf = wsum(ssdf); ssdf2 = wsum(ssdf2); c50 = wsum(c50);
    samp = wsum(samp); samp2 = wsum(samp2);
    hmx = wmaxr(hmx); hmn = wminr(hmn);
    if (lane == 0){
      s_red[0][w]=srr; s_red[1][w]=srr2; s_red[2][w]=shr; s_red[3][w]=shr2;
      s_red[4][w]=ssdf; s_red[5][w]=ssdf2; s_red[6][w]=c50;
      s_red[7][w]=samp; s_red[8][w]=samp2; s_red[9][w]=hmx; s_red[10][w]=hmn;
    }
  }
  __syncthreads();   // [D]

  // HRV finals by tid 128 only -> stash
  if (tid == 128){
    float Srr=0.f, Srr2=0.f, Shr=0.f, Shr2=0.f, Ssdf=0.f, Ssdf2=0.f;
    float C50=0.f, Samp=0.f, Samp2=0.f, Hmx=-INFINITY, Hmn=INFINITY;
#pragma unroll
    for (int j = 0; j < NW; ++j){
      Srr += s_red[0][j]; Srr2 += s_red[1][j]; Shr += s_red[2][j]; Shr2 += s_red[3][j];
      Ssdf += s_red[4][j]; Ssdf2 += s_red[5][j]; C50 += s_red[6][j];
      Samp += s_red[7][j]; Samp2 += s_red[8][j];
      Hmx = fmaxf(Hmx, s_red[9][j]); Hmn = fminf(Hmn, s_red[10][j]);
    }
    const bool g1 = npk >= 1, g2 = npk >= 2, g3 = npk >= 3;
    const float dnr = fmaxf((float)nr, 1.0f);
    const float dns = fmaxf((float)ns, 1.0f);
    const float dnp = fmaxf((float)npk, 1.0f);
    float mean_rr = Srr / dnr;
    float msdf = Ssdf / dns;
    float mhr0 = Shr / dnr;
    float amp_mean = Samp / dnp;
    float amp_std = sqrtf(fmaxf(Samp2/dnp - amp_mean*amp_mean, 0.f));
    s_stash[6]  = g2 ? sqrtf(fmaxf(Srr2/dnr - mean_rr*mean_rr, 0.f)) : 0.f;  // sdnn
    s_stash[7]  = g3 ? sqrtf(fmaxf(Ssdf2/dns, 0.f)) : 0.f;                   // rmssd
    s_stash[8]  = g3 ? (C50 / dns * 100.0f) : 0.f;                           // pnn50
    s_stash[9]  = g3 ? sqrtf(fmaxf(Ssdf2/dns - msdf*msdf, 0.f)) : 0.f;       // sdsd
    s_stash[10] = g1 ? amp_mean : 0.f;
    s_stash[11] = g1 ? amp_std : 0.f;
    s_stash[12] = (g1 && amp_mean != 0.f) ? amp_std / amp_mean * 100.0f : 0.f;
    s_stash[13] = (g2 && mean_rr > 0.f) ? 60.0f / fmaxf(mean_rr, 1e-6f) : 0.f; // mean_hr
    s_stash[14] = g2 ? sqrtf(fmaxf(Shr2/dnr - mhr0*mhr0, 0.f)) : 0.f;        // std_hr
    s_stash[15] = g2 ? (Hmx - Hmn) : 0.f;                                    // hr_rng
  }

  // ---- interp to 4 Hz + Welch band powers (only when cond) ----
  float t_last = (npk >= 1) ? (float)(s_pk[npk-1]-s_pk[0]) * INVFS : 0.0f;
  const bool cond = (npk >= 3) && (t_last * 4.0f > 10.0f);  // uniform per block
  if (cond){
    const int p0 = s_pk[0];
    for (int g = tid; g < GLEN; g += NB){
      float t = (float)g * 0.25f;
      int lo = 0, hi = npk - 1;
      while (lo < hi){
        int mid = (lo + hi + 1) >> 1;
        float tk = (float)(s_pk[mid]-p0) * INVFS;
        if (tk <= t) lo = mid; else hi = mid - 1;
      }
      int j = lo;
      float vv;
      if (j >= npk-1){
        vv = (float)(s_pk[npk-1]-s_pk[npk-2]) * INVFS;  // v_last
      } else {
        float t0 = (float)(s_pk[j]-p0) * INVFS;
        float t1 = (float)(s_pk[j+1]-p0) * INVFS;
        float v0 = (j == 0) ? (float)(s_pk[1]-s_pk[0]) * INVFS
                            : (float)(s_pk[j]-s_pk[j-1]) * INVFS;
        float v1 = (float)(s_pk[j+1]-s_pk[j]) * INVFS;
        vv = v0 + (t - t0) * (v1 - v0) / (t1 - t0);
      }
      s_rri[g] = vv;
    }
    __syncthreads();   // [E]
    // segment means (seg0 = rri[0:256], seg1 = rri[128:384])
    float v0 = (tid < 256) ? s_rri[tid] : 0.f;
    float v1 = (tid < 256) ? s_rri[128 + tid] : 0.f;
    v0 = wsum(v0); v1 = wsum(v1);
    if (lane == 0){ s_red[0][w] = v0; s_red[1][w] = v1; }
    __syncthreads();   // [F]
    float me0 = 0.f, me1 = 0.f;
#pragma unroll
    for (int j = 0; j < NW; ++j){ me0 += s_red[0][j]; me1 += s_red[1][j]; }
    me0 *= (1.0f/256.0f); me1 *= (1.0f/256.0f);
    // direct DFT at bins 3..25 for both segments: 46 (seg,bin) pairs over 6 waves
    for (int p = w; p < 46; p += NW){
      int k = 3 + (p >> 1);
      int so = (p & 1) * 128;
      float ms = (p & 1) ? me1 : me0;
      float re = 0.f, im = 0.f;
#pragma unroll
      for (int q = 0; q < 4; ++q){
        int n = lane + (q << 6);
        float xv = (s_rri[so + n] - ms) * (0.5f - 0.5f*s_cs[n]);  // Hann
        int ti = (k * n) & 255;
        re += xv * s_cs[ti];
        im -= xv * s_sn[ti];
      }
      re = wsum(re); im = wsum(im);
      if (lane == 0) s_pw[p] = (re*re + im*im) * (2.0f/384.0f);  // *2 * 1/(4*96)
    }
  }
  __syncthreads();   // [G] unconditional: covers stash/s_rf/s_pw -> epilogue

  // ---- epilogue ----
  if (tid == 0){
    const bool g2 = npk >= 2;
    int limit = npk - 1;
    if (limit > 5) limit = 5;
    if (limit < 0) limit = 0;
    const float dlim = fmaxf((float)limit, 1.0f);
    float rise_t = g2 ? (s_rf[0]+s_rf[1]+s_rf[2]+s_rf[3]+s_rf[4]) / dlim : 0.f;
    float fall_t = g2 ? (s_rf[5]+s_rf[6]+s_rf[7]+s_rf[8]+s_rf[9]) / dlim : 0.f;
    float lf = 0.f, hf = 0.f, lfhf = 0.f;
    if (cond){
      const float df = 0.015625f;
      float acc = 0.f;
      for (int k = 3; k <= 9; ++k){
        float pk2 = 0.5f*(s_pw[2*(k-3)] + s_pw[2*(k-3)+1]);
        acc += (k == 3 || k == 9) ? 0.5f*pk2 : pk2;
      }
      lf = acc * df;
      acc = 0.f;
      for (int k = 10; k <= 25; ++k){
        float pk2 = 0.5f*(s_pw[2*(k-3)] + s_pw[2*(k-3)+1]);
        acc += (k == 10 || k == 25) ? 0.5f*pk2 : pk2;
      }
      hf = acc * df;
      if (hf > 0.f) lfhf = lf / fmaxf(hf, 1e-12f);
    }
    float feats[23] = {s_stash[0], s_stash[1], s_stash[2], s_stash[3],
                       s_stash[4], s_stash[5], s_stash[5]-s_stash[4],
                       s_stash[6], s_stash[7], s_stash[8], s_stash[9],
                       lf, hf, lfhf,
                       s_stash[10], s_stash[11], s_stash[12],
                       rise_t, fall_t,
                       s_stash[13], s_stash[14], s_stash[15], (float)npk};
    float* o = out + (size_t)b * 23;
#pragma unroll
    for (int i = 0; i < 23; ++i){
      float vv = feats[i];
      o[i] = (vv == vv && fabsf(vv) != INFINITY) ? vv : 0.0f;  // nan_to_num
    }
  }
}

extern "C" void kernel_launch(void* const* d_in, const int* in_sizes, int n_in,
                              void* d_out, int out_size, void* d_ws, size_t ws_size,
                              hipStream_t stream){
  const float* x = (const float*)d_in[0];
  float* out = (float*)d_out;
  const int B = in_sizes[0] / TLEN;
  bvp_feat_kernel<<<dim3(B), dim3(NB), 0, stream>>>(x, out);
}

// Round 7
// 107.716 us; speedup vs baseline: 2.5701x; 1.0778x over previous
//
#include <hip/hip_runtime.h>
#include <math.h>

#define TLEN 7680
#define NB 384
#define NW 6          // waves per block
#define CHUNK 20      // TLEN / NB ; CHUNK > DIST-1=19 => window spans <=1 neighbor chunk
#define KMAX 386      // T//DIST + 2
#define GUSE 384      // Welch uses rri[0:256] and rri[128:384] only

__device__ __forceinline__ float wsum(float v){
#pragma unroll
  for (int o = 32; o; o >>= 1) v += __shfl_xor(v, o);
  return v;
}
__device__ __forceinline__ float wmaxr(float v){
#pragma unroll
  for (int o = 32; o; o >>= 1) v = fmaxf(v, __shfl_xor(v, o));
  return v;
}
__device__ __forceinline__ float wminr(float v){
#pragma unroll
  for (int o = 32; o; o >>= 1) v = fminf(v, __shfl_xor(v, o));
  return v;
}
// hardware trig, input in revolutions in [0,1): D = sin/cos(2*pi*S0)
__device__ __forceinline__ float hw_sin_rev(float t){
  float r; asm("v_sin_f32 %0, %1" : "=v"(r) : "v"(t)); return r;
}
__device__ __forceinline__ float hw_cos_rev(float t){
  float r; asm("v_cos_f32 %0, %1" : "=v"(r) : "v"(t)); return r;
}

__global__ __launch_bounds__(NB, 4)
void bvp_feat_kernel(const float* __restrict__ x, float* __restrict__ out){
  const int tid = threadIdx.x;
  const int lane = tid & 63;
  const int w = tid >> 6;
  const int b = blockIdx.x;

  __shared__ __align__(16) float s_bvp[TLEN];   // after barrier [D]: first 384 floats reused as s_rri
  __shared__ unsigned short s_pk[KMAX];
  __shared__ float s_red[11][NW];
  __shared__ int   s_wtot[NW];
  __shared__ float s_pw[46];
  __shared__ float s_rf[10];
  __shared__ float s_stash[16];   // uniform per-block scalars, LDS-resident
  float* const s_rri = s_bvp;     // alias: s_bvp dead after [D]

  // ---- load row into LDS, fused raw moments + min/max ----
  float m1 = 0.f, m2 = 0.f, m3 = 0.f, m4 = 0.f;
  float vmn = INFINITY, vmx = -INFINITY;
  const float4* row4 = (const float4*)(x + (size_t)b * TLEN);
  float4* s4 = (float4*)s_bvp;
#pragma unroll
  for (int q = 0; q < TLEN/4/NB; ++q){
    int i = tid + q * NB;
    float4 v = row4[i];
    s4[i] = v;
#define ACC1(a) { float _a=(a); m1+=_a; float _q=_a*_a; m2+=_q; m3+=_q*_a; m4+=_q*_q; vmn=fminf(vmn,_a); vmx=fmaxf(vmx,_a); }
    ACC1(v.x) ACC1(v.y) ACC1(v.z) ACC1(v.w)
#undef ACC1
  }
  m1 = wsum(m1); m2 = wsum(m2); m3 = wsum(m3); m4 = wsum(m4);
  vmn = wminr(vmn); vmx = wmaxr(vmx);
  if (lane == 0){
    s_red[0][w] = m1; s_red[1][w] = m2; s_red[2][w] = m3;
    s_red[3][w] = m4; s_red[4][w] = vmn; s_red[5][w] = vmx;
  }
  __syncthreads();   // [A] also guarantees s_bvp fully populated

  // moments finalized by tid 64 only -> LDS stash
  if (tid == 64){
    float M1=0.f, M2=0.f, M3=0.f, M4=0.f, MN=INFINITY, MX=-INFINITY;
#pragma unroll
    for (int j = 0; j < NW; ++j){
      M1 += s_red[0][j]; M2 += s_red[1][j]; M3 += s_red[2][j]; M4 += s_red[3][j];
      MN = fminf(MN, s_red[4][j]); MX = fmaxf(MX, s_red[5][j]);
    }
    const float invT = 1.0f / (float)TLEN;
    float mu = M1 * invT;
    float e2 = M2*invT, e3 = M3*invT, e4 = M4*invT;
    float c2 = e2 - mu*mu;
    float c3 = e3 - 3.0f*mu*e2 + 2.0f*mu*mu*mu;
    float c4 = e4 - 4.0f*mu*e3 + 6.0f*mu*mu*e2 - 3.0f*mu*mu*mu*mu;
    float m2c = fmaxf(c2, 1e-30f);
    s_stash[0] = mu;
    s_stash[1] = sqrtf(fmaxf(c2, 0.0f));
    s_stash[2] = c3 / (m2c * sqrtf(m2c));
    s_stash[3] = c4 / (m2c * m2c) - 3.0f;
    s_stash[4] = MN;
    s_stash[5] = MX;
  }

  // ---- peak detection: chunk-local window max (CHUNK=20 > DIST-1) ----
  const int base = tid * CHUNK;
  const bool has_prev = (tid > 0);
  const bool has_next = (tid < NB-1);
  float v[CHUNK];
  {
    const float4* sb4 = (const float4*)(s_bvp + base);   // 16B aligned
#pragma unroll
    for (int q = 0; q < 5; ++q){
      float4 t4 = sb4[q];
      v[4*q+0]=t4.x; v[4*q+1]=t4.y; v[4*q+2]=t4.z; v[4*q+3]=t4.w;
    }
  }
  float M = v[0];
#pragma unroll
  for (int j = 1; j < CHUNK; ++j) M = fmaxf(M, v[j]);

  unsigned cmask = 0u;
  {
    float pn = -INFINITY;
    float next0 = 0.0f;
    float4 nq;
    const float4* nb4 = (const float4*)(s_bvp + (has_next ? base + CHUNK : 0));
    float prevs0 = has_prev ? s_bvp[base-1] : 0.0f;
#pragma unroll
    for (int o = 0; o < CHUNK; ++o){
      if (o >= 1){
        const int j = o - 1;
        if ((j & 3) == 0) nq = nb4[j >> 2];
        float nv = ((j&3)==0) ? nq.x : ((j&3)==1) ? nq.y : ((j&3)==2) ? nq.z : nq.w;
        if (o == 1) next0 = nv;
        if (has_next) pn = fmaxf(pn, nv);
      }
      float cur = v[o];
      float prevs = (o == 0) ? prevs0 : v[o-1];
      float nxts  = (o == CHUNK-1) ? next0 : v[o+1];
      bool edge_ok = (base + o >= 1) && (base + o + 1 < TLEN);
      if (edge_ok && cur > prevs && cur > nxts && cur >= M && cur >= pn)
        cmask |= (1u << o);
    }
  }
  unsigned pmask = 0u;
  int pcnt = 0;
  {
    float sp = -INFINITY;
    float4 pq;
    const float4* pb4 = (const float4*)(s_bvp + (has_prev ? base - CHUNK : 0));
#pragma unroll
    for (int o = CHUNK-1; o >= 0; --o){
      if (((cmask >> o) & 1u) && (v[o] >= sp)){ pmask |= (1u << o); ++pcnt; }
      if (o > 0){
        if ((o & 3) == 3 || o == CHUNK-1) pq = pb4[o >> 2];
        float pv = ((o&3)==0) ? pq.x : ((o&3)==1) ? pq.y : ((o&3)==2) ? pq.z : pq.w;
        if (has_prev) sp = fmaxf(sp, pv);
      }
    }
  }

  // ---- compact peak indices: wave shuffle scan + 1 barrier ----
  int scan = pcnt;
#pragma unroll
  for (int off = 1; off < 64; off <<= 1){
    int t = __shfl_up(scan, off);
    if (lane >= off) scan += t;
  }
  if (lane == 63) s_wtot[w] = scan;
  __syncthreads();   // [B]
  int wbase = 0, total = 0;
#pragma unroll
  for (int j = 0; j < NW; ++j){ if (j < w) wbase += s_wtot[j]; total += s_wtot[j]; }
  const int npk = total < KMAX ? total : KMAX;
  {
    int pos = wbase + scan - pcnt;  // exclusive prefix
    unsigned mm = pmask;
    while (mm){
      int o = __ffs(mm) - 1;
      mm &= mm - 1u;
      if (pos < KMAX) s_pk[pos] = (unsigned short)(base + o);
      ++pos;
    }
  }
  __syncthreads();   // [C]

  // ---- rise/fall over first min(npk-1, 5) peaks ----
  const float INVFS = 1.0f/64.0f;
  if (tid < 5){
    int limit = npk - 1;
    if (limit > 5) limit = 5;
    float rise = 0.f, fall = 0.f;
    if (tid < limit){
      int pk = (int)s_pk[tid];
      float best = INFINITY; int am = 0;
      for (int off = 0; off < 20; ++off){
        int bi = pk - 20 + off;
        float vv = (bi >= 0) ? s_bvp[bi] : INFINITY;
        if (vv < best){ best = vv; am = off; }
      }
      rise = (float)(20 - am) * INVFS;
      best = INFINITY; am = 0;
      for (int off = 0; off < 20; ++off){
        int fi = pk + off;
        float vv = (fi < TLEN) ? s_bvp[fi] : INFINITY;
        if (vv < best){ best = vv; am = off; }
      }
      fall = (float)am * INVFS;
    }
    s_rf[tid] = rise;
    s_rf[5 + tid] = fall;
  }

  // ---- RR / HRV stats: single pass, raw moments ----
  const int nr = npk > 1 ? npk - 1 : 0;
  const int ns = npk > 2 ? npk - 2 : 0;
  {
    float srr=0.f, srr2=0.f, shr=0.f, shr2=0.f;
    float ssdf=0.f, ssdf2=0.f, c50=0.f, samp=0.f, samp2=0.f;
    float hmx = -INFINITY, hmn = INFINITY;
    for (int i = tid; i < nr; i += NB){
      float rr = (float)((int)s_pk[i+1]-(int)s_pk[i]) * INVFS;
      srr += rr; srr2 += rr*rr;
      float hr = 60.0f / fmaxf(rr, 1e-6f);
      shr += hr; shr2 += hr*hr;
      hmx = fmaxf(hmx, hr); hmn = fminf(hmn, hr);
    }
    for (int i = tid; i < ns; i += NB){
      float r0 = (float)((int)s_pk[i+1]-(int)s_pk[i]) * INVFS;
      float r1 = (float)((int)s_pk[i+2]-(int)s_pk[i+1]) * INVFS;
      float d = r1 - r0;
      ssdf += d; ssdf2 += d*d;
      if (fabsf(d) > 0.05f) c50 += 1.0f;
    }
    for (int i = tid; i < npk; i += NB){
      float a = s_bvp[(int)s_pk[i]];
      samp += a; samp2 += a*a;
    }
    srr = wsum(srr); srr2 = wsum(srr2); shr = wsum(shr); shr2 = wsum(shr2);
    ssdf = wsum(ssdf); ssdf2 = wsum(ssdf2); c50 = wsum(c50);
    samp = wsum(samp); samp2 = wsum(samp2);
    hmx = wmaxr(hmx); hmn = wminr(hmn);
    if (lane == 0){
      s_red[0][w]=srr; s_red[1][w]=srr2; s_red[2][w]=shr; s_red[3][w]=shr2;
      s_red[4][w]=ssdf; s_red[5][w]=ssdf2; s_red[6][w]=c50;
      s_red[7][w]=samp; s_red[8][w]=samp2; s_red[9][w]=hmx; s_red[10][w]=hmn;
    }
  }
  __syncthreads();   // [D]  (s_bvp dead past here -> s_rri may overwrite)

  // HRV finals by tid 128 only -> stash
  if (tid == 128){
    float Srr=0.f, Srr2=0.f, Shr=0.f, Shr2=0.f, Ssdf=0.f, Ssdf2=0.f;
    float C50=0.f, Samp=0.f, Samp2=0.f, Hmx=-INFINITY, Hmn=INFINITY;
#pragma unroll
    for (int j = 0; j < NW; ++j){
      Srr += s_red[0][j]; Srr2 += s_red[1][j]; Shr += s_red[2][j]; Shr2 += s_red[3][j];
      Ssdf += s_red[4][j]; Ssdf2 += s_red[5][j]; C50 += s_red[6][j];
      Samp += s_red[7][j]; Samp2 += s_red[8][j];
      Hmx = fmaxf(Hmx, s_red[9][j]); Hmn = fminf(Hmn, s_red[10][j]);
    }
    const bool g1 = npk >= 1, g2 = npk >= 2, g3 = npk >= 3;
    const float dnr = fmaxf((float)nr, 1.0f);
    const float dns = fmaxf((float)ns, 1.0f);
    const float dnp = fmaxf((float)npk, 1.0f);
    float mean_rr = Srr / dnr;
    float msdf = Ssdf / dns;
    float mhr0 = Shr / dnr;
    float amp_mean = Samp / dnp;
    float amp_std = sqrtf(fmaxf(Samp2/dnp - amp_mean*amp_mean, 0.f));
    s_stash[6]  = g2 ? sqrtf(fmaxf(Srr2/dnr - mean_rr*mean_rr, 0.f)) : 0.f;  // sdnn
    s_stash[7]  = g3 ? sqrtf(fmaxf(Ssdf2/dns, 0.f)) : 0.f;                   // rmssd
    s_stash[8]  = g3 ? (C50 / dns * 100.0f) : 0.f;                           // pnn50
    s_stash[9]  = g3 ? sqrtf(fmaxf(Ssdf2/dns - msdf*msdf, 0.f)) : 0.f;       // sdsd
    s_stash[10] = g1 ? amp_mean : 0.f;
    s_stash[11] = g1 ? amp_std : 0.f;
    s_stash[12] = (g1 && amp_mean != 0.f) ? amp_std / amp_mean * 100.0f : 0.f;
    s_stash[13] = (g2 && mean_rr > 0.f) ? 60.0f / fmaxf(mean_rr, 1e-6f) : 0.f; // mean_hr
    s_stash[14] = g2 ? sqrtf(fmaxf(Shr2/dnr - mhr0*mhr0, 0.f)) : 0.f;        // std_hr
    s_stash[15] = g2 ? (Hmx - Hmn) : 0.f;                                    // hr_rng
  }

  // ---- interp to 4 Hz + Welch band powers (only when cond) ----
  float t_last = (npk >= 1) ? (float)((int)s_pk[npk-1]-(int)s_pk[0]) * INVFS : 0.0f;
  const bool cond = (npk >= 3) && (t_last * 4.0f > 10.0f);  // uniform per block
  if (cond){
    const int p0 = (int)s_pk[0];
    {
      const int g = tid;   // GUSE == NB: one sample per thread
      float t = (float)g * 0.25f;
      int lo = 0, hi = npk - 1;
      while (lo < hi){
        int mid = (lo + hi + 1) >> 1;
        float tk = (float)((int)s_pk[mid]-p0) * INVFS;
        if (tk <= t) lo = mid; else hi = mid - 1;
      }
      int j = lo;
      float vv;
      if (j >= npk-1){
        vv = (float)((int)s_pk[npk-1]-(int)s_pk[npk-2]) * INVFS;  // v_last
      } else {
        float t0 = (float)((int)s_pk[j]-p0) * INVFS;
        float t1 = (float)((int)s_pk[j+1]-p0) * INVFS;
        float v0 = (j == 0) ? (float)((int)s_pk[1]-(int)s_pk[0]) * INVFS
                            : (float)((int)s_pk[j]-(int)s_pk[j-1]) * INVFS;
        float v1 = (float)((int)s_pk[j+1]-(int)s_pk[j]) * INVFS;
        vv = v0 + (t - t0) * (v1 - v0) / (t1 - t0);
      }
      s_rri[g] = vv;
    }
    __syncthreads();   // [E]
    // segment means (seg0 = rri[0:256], seg1 = rri[128:384])
    float v0 = (tid < 256) ? s_rri[tid] : 0.f;
    float v1 = (tid < 256) ? s_rri[128 + tid] : 0.f;
    v0 = wsum(v0); v1 = wsum(v1);
    if (lane == 0){ s_red[0][w] = v0; s_red[1][w] = v1; }
    __syncthreads();   // [F]
    float me0 = 0.f, me1 = 0.f;
#pragma unroll
    for (int j = 0; j < NW; ++j){ me0 += s_red[0][j]; me1 += s_red[1][j]; }
    me0 *= (1.0f/256.0f); me1 *= (1.0f/256.0f);
    // hoist windowed samples (bin-independent): n = lane + 64q
    float xw0[4], xw1[4];
#pragma unroll
    for (int q = 0; q < 4; ++q){
      int n = lane + (q << 6);
      float hann = 0.5f - 0.5f * hw_cos_rev((float)n * (1.0f/256.0f));
      xw0[q] = (s_rri[n]       - me0) * hann;
      xw1[q] = (s_rri[128 + n] - me1) * hann;
    }
    // direct DFT at bins 3..25, both segments per bin; twiddles via HW trig
    for (int kk = w; kk < 23; kk += NW){
      int k = kk + 3;
      float re0=0.f, im0=0.f, re1=0.f, im1=0.f;
#pragma unroll
      for (int q = 0; q < 4; ++q){
        int n = lane + (q << 6);
        float t = (float)((k * n) & 255) * (1.0f/256.0f);
        float s = hw_sin_rev(t);
        float c = hw_cos_rev(t);
        re0 += xw0[q]*c; im0 -= xw0[q]*s;
        re1 += xw1[q]*c; im1 -= xw1[q]*s;
      }
      re0 = wsum(re0); im0 = wsum(im0); re1 = wsum(re1); im1 = wsum(im1);
      if (lane == 0){
        s_pw[2*kk]   = (re0*re0 + im0*im0) * (2.0f/384.0f);  // *2 interior-bin * 1/(4*96)
        s_pw[2*kk+1] = (re1*re1 + im1*im1) * (2.0f/384.0f);
      }
    }
  }
  __syncthreads();   // [G] unconditional: covers stash/s_rf/s_pw -> epilogue

  // ---- epilogue ----
  if (tid == 0){
    const bool g2 = npk >= 2;
    int limit = npk - 1;
    if (limit > 5) limit = 5;
    if (limit < 0) limit = 0;
    const float dlim = fmaxf((float)limit, 1.0f);
    float rise_t = g2 ? (s_rf[0]+s_rf[1]+s_rf[2]+s_rf[3]+s_rf[4]) / dlim : 0.f;
    float fall_t = g2 ? (s_rf[5]+s_rf[6]+s_rf[7]+s_rf[8]+s_rf[9]) / dlim : 0.f;
    float lf = 0.f, hf = 0.f, lfhf = 0.f;
    if (cond){
      const float df = 0.015625f;
      float acc = 0.f;
      for (int k = 3; k <= 9; ++k){
        float pk2 = 0.5f*(s_pw[2*(k-3)] + s_pw[2*(k-3)+1]);
        acc += (k == 3 || k == 9) ? 0.5f*pk2 : pk2;
      }
      lf = acc * df;
      acc = 0.f;
      for (int k = 10; k <= 25; ++k){
        float pk2 = 0.5f*(s_pw[2*(k-3)] + s_pw[2*(k-3)+1]);
        acc += (k == 10 || k == 25) ? 0.5f*pk2 : pk2;
      }
      hf = acc * df;
      if (hf > 0.f) lfhf = lf / fmaxf(hf, 1e-12f);
    }
    float feats[23] = {s_stash[0], s_stash[1], s_stash[2], s_stash[3],
                       s_stash[4], s_stash[5], s_stash[5]-s_stash[4],
                       s_stash[6], s_stash[7], s_stash[8], s_stash[9],
                       lf, hf, lfhf,
                       s_stash[10], s_stash[11], s_stash[12],
                       rise_t, fall_t,
                       s_stash[13], s_stash[14], s_stash[15], (float)npk};
    float* o = out + (size_t)b * 23;
#pragma unroll
    for (int i = 0; i < 23; ++i){
      float vv = feats[i];
      o[i] = (vv == vv && fabsf(vv) != INFINITY) ? vv : 0.0f;  // nan_to_num
    }
  }
}

extern "C" void kernel_launch(void* const* d_in, const int* in_sizes, int n_in,
                              void* d_out, int out_size, void* d_ws, size_t ws_size,
                              hipStream_t stream){
  const float* x = (const float*)d_in[0];
  float* out = (float*)d_out;
  const int B = in_sizes[0] / TLEN;
  bvp_feat_kernel<<<dim3(B), dim3(NB), 0, stream>>>(x, out);
}

// Round 8
// 104.527 us; speedup vs baseline: 2.6485x; 1.0305x over previous
//
#include <hip/hip_runtime.h>
#include <math.h>

#define TLEN 7680
#define NB 384
#define NW 6          // waves per block
#define CHUNK 20      // TLEN / NB ; CHUNK > DIST-1=19 => window spans <=1 neighbor chunk
#define KMAX 386      // T//DIST + 2

__device__ __forceinline__ float wsum(float v){
#pragma unroll
  for (int o = 32; o; o >>= 1) v += __shfl_xor(v, o);
  return v;
}
__device__ __forceinline__ float wmaxr(float v){
#pragma unroll
  for (int o = 32; o; o >>= 1) v = fmaxf(v, __shfl_xor(v, o));
  return v;
}
__device__ __forceinline__ float wminr(float v){
#pragma unroll
  for (int o = 32; o; o >>= 1) v = fminf(v, __shfl_xor(v, o));
  return v;
}
// hardware trig, input in revolutions in [0,1): D = sin/cos(2*pi*S0)
__device__ __forceinline__ float hw_sin_rev(float t){
  float r; asm("v_sin_f32 %0, %1" : "=v"(r) : "v"(t)); return r;
}
__device__ __forceinline__ float hw_cos_rev(float t){
  float r; asm("v_cos_f32 %0, %1" : "=v"(r) : "v"(t)); return r;
}

__global__ __launch_bounds__(NB, 4)
void bvp_feat_kernel(const float* __restrict__ x, float* __restrict__ out){
  const int tid = threadIdx.x;
  const int lane = tid & 63;
  const int w = tid >> 6;
  const int b = blockIdx.x;

  __shared__ __align__(16) float s_bvp[TLEN];   // [0:384) reused as s_rri, [384:768) as tbl after [D]
  __shared__ unsigned short s_pk[KMAX];
  __shared__ float s_red[11][NW];
  __shared__ int   s_wtot[NW];
  __shared__ float s_pw[46];
  __shared__ float s_rf[10];
  __shared__ float s_stash[16];   // uniform per-block scalars, LDS-resident
  float* const s_rri = s_bvp;                          // alias (dead data)
  unsigned short* const tbl = (unsigned short*)(s_bvp + 384);  // alias (dead data)

  // ---- P0: chunk-direct load from global + fused raw moments, stage to LDS ----
  const int base = tid * CHUNK;
  float v[CHUNK];
  {
    const float4* src4 = (const float4*)(x + (size_t)b * TLEN + base);  // 80B/lane, 16B aligned
    float4* dst4 = (float4*)(s_bvp + base);
    float m1=0.f, m2=0.f, m3=0.f, m4=0.f, vmn=INFINITY, vmx=-INFINITY;
#pragma unroll
    for (int q = 0; q < 5; ++q){
      float4 t4 = src4[q];
      dst4[q] = t4;
      v[4*q+0]=t4.x; v[4*q+1]=t4.y; v[4*q+2]=t4.z; v[4*q+3]=t4.w;
    }
#pragma unroll
    for (int j = 0; j < CHUNK; ++j){
      float a = v[j]; float q = a*a;
      m1 += a; m2 += q; m3 += q*a; m4 += q*q;
      vmn = fminf(vmn, a); vmx = fmaxf(vmx, a);
    }
    m1 = wsum(m1); m2 = wsum(m2); m3 = wsum(m3); m4 = wsum(m4);
    vmn = wminr(vmn); vmx = wmaxr(vmx);
    if (lane == 0){
      s_red[0][w]=m1; s_red[1][w]=m2; s_red[2][w]=m3;
      s_red[3][w]=m4; s_red[4][w]=vmn; s_red[5][w]=vmx;
    }
  }
  __syncthreads();   // [AB] s_bvp fully staged; moment partials visible

  // moments finalized by tid 64 -> stash (runs before its peak work; wave-local lag only)
  if (tid == 64){
    float M1=0.f, M2=0.f, M3=0.f, M4=0.f, MN=INFINITY, MX=-INFINITY;
#pragma unroll
    for (int j = 0; j < NW; ++j){
      M1 += s_red[0][j]; M2 += s_red[1][j]; M3 += s_red[2][j]; M4 += s_red[3][j];
      MN = fminf(MN, s_red[4][j]); MX = fmaxf(MX, s_red[5][j]);
    }
    const float invT = 1.0f / (float)TLEN;
    float mu = M1 * invT;
    float e2 = M2*invT, e3 = M3*invT, e4 = M4*invT;
    float c2 = e2 - mu*mu;
    float c3 = e3 - 3.0f*mu*e2 + 2.0f*mu*mu*mu;
    float c4 = e4 - 4.0f*mu*e3 + 6.0f*mu*mu*e2 - 3.0f*mu*mu*mu*mu;
    float m2c = fmaxf(c2, 1e-30f);
    s_stash[0] = mu;
    s_stash[1] = sqrtf(fmaxf(c2, 0.0f));
    s_stash[2] = c3 / (m2c * sqrtf(m2c));
    s_stash[3] = c4 / (m2c * m2c) - 3.0f;
    s_stash[4] = MN;
    s_stash[5] = MX;
  }

  // ---- P1: peak detection (v[] already in regs; neighbors from LDS) ----
  const bool has_prev = (tid > 0);
  const bool has_next = (tid < NB-1);
  float M = v[0];
#pragma unroll
  for (int j = 1; j < CHUNK; ++j) M = fmaxf(M, v[j]);

  unsigned cmask = 0u;
  {
    float pn = -INFINITY;
    float next0 = 0.0f;
    float4 nq;
    const float4* nb4 = (const float4*)(s_bvp + (has_next ? base + CHUNK : 0));
    float prevs0 = has_prev ? s_bvp[base-1] : 0.0f;
#pragma unroll
    for (int o = 0; o < CHUNK; ++o){
      if (o >= 1){
        const int j = o - 1;
        if ((j & 3) == 0) nq = nb4[j >> 2];
        float nv = ((j&3)==0) ? nq.x : ((j&3)==1) ? nq.y : ((j&3)==2) ? nq.z : nq.w;
        if (o == 1) next0 = nv;
        if (has_next) pn = fmaxf(pn, nv);
      }
      float cur = v[o];
      float prevs = (o == 0) ? prevs0 : v[o-1];
      float nxts  = (o == CHUNK-1) ? next0 : v[o+1];
      bool edge_ok = (base + o >= 1) && (base + o + 1 < TLEN);
      if (edge_ok && cur > prevs && cur > nxts && cur >= M && cur >= pn)
        cmask |= (1u << o);
    }
  }
  unsigned pmask = 0u;
  int pcnt = 0;
  {
    float sp = -INFINITY;
    float4 pq;
    const float4* pb4 = (const float4*)(s_bvp + (has_prev ? base - CHUNK : 0));
#pragma unroll
    for (int o = CHUNK-1; o >= 0; --o){
      if (((cmask >> o) & 1u) && (v[o] >= sp)){ pmask |= (1u << o); ++pcnt; }
      if (o > 0){
        if ((o & 3) == 3 || o == CHUNK-1) pq = pb4[o >> 2];
        float pv = ((o&3)==0) ? pq.x : ((o&3)==1) ? pq.y : ((o&3)==2) ? pq.z : pq.w;
        if (has_prev) sp = fmaxf(sp, pv);
      }
    }
  }

  // wave shuffle scan
  int scan = pcnt;
#pragma unroll
  for (int off = 1; off < 64; off <<= 1){
    int t = __shfl_up(scan, off);
    if (lane >= off) scan += t;
  }
  if (lane == 63) s_wtot[w] = scan;
  __syncthreads();   // [B]

  // ---- P2: compact peak indices ----
  int wbase = 0, total = 0;
#pragma unroll
  for (int j = 0; j < NW; ++j){ if (j < w) wbase += s_wtot[j]; total += s_wtot[j]; }
  const int npk = total < KMAX ? total : KMAX;
  {
    int pos = wbase + scan - pcnt;  // exclusive prefix
    unsigned mm = pmask;
    while (mm){
      int o = __ffs(mm) - 1;
      mm &= mm - 1u;
      if (pos < KMAX) s_pk[pos] = (unsigned short)(base + o);
      ++pos;
    }
  }
  __syncthreads();   // [C]

  // ---- P3: rise/fall (tid<5) + HRV single-pass raw moments ----
  const float INVFS = 1.0f/64.0f;
  if (tid < 5){
    int limit = npk - 1;
    if (limit > 5) limit = 5;
    float rise = 0.f, fall = 0.f;
    if (tid < limit){
      int pk = (int)s_pk[tid];
      float best = INFINITY; int am = 0;
      for (int off = 0; off < 20; ++off){
        int bi = pk - 20 + off;
        float vv = (bi >= 0) ? s_bvp[bi] : INFINITY;
        if (vv < best){ best = vv; am = off; }
      }
      rise = (float)(20 - am) * INVFS;
      best = INFINITY; am = 0;
      for (int off = 0; off < 20; ++off){
        int fi = pk + off;
        float vv = (fi < TLEN) ? s_bvp[fi] : INFINITY;
        if (vv < best){ best = vv; am = off; }
      }
      fall = (float)am * INVFS;
    }
    s_rf[tid] = rise;
    s_rf[5 + tid] = fall;
  }
  const int nr = npk > 1 ? npk - 1 : 0;
  const int ns = npk > 2 ? npk - 2 : 0;
  {
    float srr=0.f, srr2=0.f, shr=0.f, shr2=0.f;
    float ssdf=0.f, ssdf2=0.f, c50=0.f, samp=0.f, samp2=0.f;
    float hmx = -INFINITY, hmn = INFINITY;
    for (int i = tid; i < nr; i += NB){
      float rr = (float)((int)s_pk[i+1]-(int)s_pk[i]) * INVFS;
      srr += rr; srr2 += rr*rr;
      float hr = 60.0f / fmaxf(rr, 1e-6f);
      shr += hr; shr2 += hr*hr;
      hmx = fmaxf(hmx, hr); hmn = fminf(hmn, hr);
    }
    for (int i = tid; i < ns; i += NB){
      float r0 = (float)((int)s_pk[i+1]-(int)s_pk[i]) * INVFS;
      float r1 = (float)((int)s_pk[i+2]-(int)s_pk[i+1]) * INVFS;
      float d = r1 - r0;
      ssdf += d; ssdf2 += d*d;
      if (fabsf(d) > 0.05f) c50 += 1.0f;
    }
    for (int i = tid; i < npk; i += NB){
      float a = s_bvp[(int)s_pk[i]];
      samp += a; samp2 += a*a;
    }
    srr = wsum(srr); srr2 = wsum(srr2); shr = wsum(shr); shr2 = wsum(shr2);
    ssdf = wsum(ssdf); ssdf2 = wsum(ssdf2); c50 = wsum(c50);
    samp = wsum(samp); samp2 = wsum(samp2);
    hmx = wmaxr(hmx); hmn = wminr(hmn);
    if (lane == 0){
      s_red[0][w]=srr; s_red[1][w]=srr2; s_red[2][w]=shr; s_red[3][w]=shr2;
      s_red[4][w]=ssdf; s_red[5][w]=ssdf2; s_red[6][w]=c50;
      s_red[7][w]=samp; s_red[8][w]=samp2; s_red[9][w]=hmx; s_red[10][w]=hmn;
    }
  }
  __syncthreads();   // [D]  (raw s_bvp dead past here)

  // ---- P4: HRV finalize (tid 128) + interp knot table build ----
  if (tid == 128){
    float Srr=0.f, Srr2=0.f, Shr=0.f, Shr2=0.f, Ssdf=0.f, Ssdf2=0.f;
    float C50=0.f, Samp=0.f, Samp2=0.f, Hmx=-INFINITY, Hmn=INFINITY;
#pragma unroll
    for (int j = 0; j < NW; ++j){
      Srr += s_red[0][j]; Srr2 += s_red[1][j]; Shr += s_red[2][j]; Shr2 += s_red[3][j];
      Ssdf += s_red[4][j]; Ssdf2 += s_red[5][j]; C50 += s_red[6][j];
      Samp += s_red[7][j]; Samp2 += s_red[8][j];
      Hmx = fmaxf(Hmx, s_red[9][j]); Hmn = fminf(Hmn, s_red[10][j]);
    }
    const bool g1 = npk >= 1, g2 = npk >= 2, g3 = npk >= 3;
    const float dnr = fmaxf((float)nr, 1.0f);
    const float dns = fmaxf((float)ns, 1.0f);
    const float dnp = fmaxf((float)npk, 1.0f);
    float mean_rr = Srr / dnr;
    float msdf = Ssdf / dns;
    float mhr0 = Shr / dnr;
    float amp_mean = Samp / dnp;
    float amp_std = sqrtf(fmaxf(Samp2/dnp - amp_mean*amp_mean, 0.f));
    s_stash[6]  = g2 ? sqrtf(fmaxf(Srr2/dnr - mean_rr*mean_rr, 0.f)) : 0.f;  // sdnn
    s_stash[7]  = g3 ? sqrtf(fmaxf(Ssdf2/dns, 0.f)) : 0.f;                   // rmssd
    s_stash[8]  = g3 ? (C50 / dns * 100.0f) : 0.f;                           // pnn50
    s_stash[9]  = g3 ? sqrtf(fmaxf(Ssdf2/dns - msdf*msdf, 0.f)) : 0.f;       // sdsd
    s_stash[10] = g1 ? amp_mean : 0.f;
    s_stash[11] = g1 ? amp_std : 0.f;
    s_stash[12] = (g1 && amp_mean != 0.f) ? amp_std / amp_mean * 100.0f : 0.f;
    s_stash[13] = (g2 && mean_rr > 0.f) ? 60.0f / fmaxf(mean_rr, 1e-6f) : 0.f; // mean_hr
    s_stash[14] = g2 ? sqrtf(fmaxf(Shr2/dnr - mhr0*mhr0, 0.f)) : 0.f;        // std_hr
    s_stash[15] = g2 ? (Hmx - Hmn) : 0.f;                                    // hr_rng
  }

  float t_last = (npk >= 1) ? (float)((int)s_pk[npk-1]-(int)s_pk[0]) * INVFS : 0.0f;
  const bool cond = (npk >= 3) && (t_last * 4.0f > 10.0f);  // uniform per block
  if (cond){
    // tbl[g] = largest j with t_knot[j] <= g/4  <=>  pk[j]-p0 <= 16g (exact ints)
    const int p0 = (int)s_pk[0];
    for (int i = tid; i < npk; i += NB){
      int glo = (i == 0) ? 0 : (((int)s_pk[i] - p0 + 15) >> 4);
      int ghi = (i == npk-1) ? 383 : ((((int)s_pk[i+1] - p0 + 15) >> 4) - 1);
      if (ghi > 383) ghi = 383;
      for (int g = glo; g <= ghi; ++g) tbl[g] = (unsigned short)i;
    }
  }
  __syncthreads();   // [D2]

  // ---- P5: interp via table + fused segment-mean partials ----
  if (cond){
    const int p0 = (int)s_pk[0];
    const int g = tid;           // one sample per thread, g in [0,384)
    float t = (float)g * 0.25f;
    int j = (int)tbl[g];
    float vv;
    if (j >= npk-1){
      vv = (float)((int)s_pk[npk-1]-(int)s_pk[npk-2]) * INVFS;  // v_last
    } else {
      float t0 = (float)((int)s_pk[j]-p0) * INVFS;
      float t1 = (float)((int)s_pk[j+1]-p0) * INVFS;
      float v0 = (j == 0) ? (float)((int)s_pk[1]-(int)s_pk[0]) * INVFS
                          : (float)((int)s_pk[j]-(int)s_pk[j-1]) * INVFS;
      float v1 = (float)((int)s_pk[j+1]-(int)s_pk[j]) * INVFS;
      vv = v0 + (t - t0) * (v1 - v0) / (t1 - t0);
    }
    s_rri[g] = vv;
    float v0p = (g < 256) ? vv : 0.f;
    float v1p = (g >= 128) ? vv : 0.f;
    v0p = wsum(v0p); v1p = wsum(v1p);
    if (lane == 0){ s_red[0][w] = v0p; s_red[1][w] = v1p; }
  }
  __syncthreads();   // [E]

  // ---- P6: Welch DFT, bins 3..25, quarter-turn twiddle rotation ----
  if (cond){
    float me0 = 0.f, me1 = 0.f;
#pragma unroll
    for (int j = 0; j < NW; ++j){ me0 += s_red[0][j]; me1 += s_red[1][j]; }
    me0 *= (1.0f/256.0f); me1 *= (1.0f/256.0f);
    float xw0[4], xw1[4];
#pragma unroll
    for (int q = 0; q < 4; ++q){
      int n = lane + (q << 6);
      float hann = 0.5f - 0.5f * hw_cos_rev((float)n * (1.0f/256.0f));
      xw0[q] = (s_rri[n]       - me0) * hann;
      xw1[q] = (s_rri[128 + n] - me1) * hann;
    }
    // theta_q = theta_0 + 90deg*(k*q mod 4)  (n = lane + 64q) => sign-permuted twiddles
    float S0a = xw0[0]-xw0[2], S1a = xw0[1]-xw0[3], T0a = xw0[0]+xw0[2], T1a = xw0[1]+xw0[3];
    float S0b = xw1[0]-xw1[2], S1b = xw1[1]-xw1[3], T0b = xw1[0]+xw1[2], T1b = xw1[1]+xw1[3];
    for (int kk = w; kk < 23; kk += NW){
      int k = kk + 3;
      float t = (float)((k * lane) & 255) * (1.0f/256.0f);
      float s = hw_sin_rev(t);
      float c = hw_cos_rev(t);
      float re0, im0, re1, im1;
      switch (k & 3){
        case 0: { float Pa=T0a+T1a, Pb=T0b+T1b;
                  re0=Pa*c; im0=-Pa*s; re1=Pb*c; im1=-Pb*s; } break;
        case 1: { re0 = S0a*c - S1a*s; im0 = -(S0a*s + S1a*c);
                  re1 = S0b*c - S1b*s; im1 = -(S0b*s + S1b*c); } break;
        case 2: { float Pa=T0a-T1a, Pb=T0b-T1b;
                  re0=Pa*c; im0=-Pa*s; re1=Pb*c; im1=-Pb*s; } break;
        default:{ re0 = S0a*c + S1a*s; im0 = S1a*c - S0a*s;
                  re1 = S0b*c + S1b*s; im1 = S1b*c - S0b*s; } break;
      }
      re0 = wsum(re0); im0 = wsum(im0); re1 = wsum(re1); im1 = wsum(im1);
      if (lane == 0){
        s_pw[2*kk]   = (re0*re0 + im0*im0) * (2.0f/384.0f);  // *2 interior-bin * 1/(4*96)
        s_pw[2*kk+1] = (re1*re1 + im1*im1) * (2.0f/384.0f);
      }
    }
  }
  __syncthreads();   // [G]

  // ---- epilogue ----
  if (tid == 0){
    const bool g2 = npk >= 2;
    int limit = npk - 1;
    if (limit > 5) limit = 5;
    if (limit < 0) limit = 0;
    const float dlim = fmaxf((float)limit, 1.0f);
    float rise_t = g2 ? (s_rf[0]+s_rf[1]+s_rf[2]+s_rf[3]+s_rf[4]) / dlim : 0.f;
    float fall_t = g2 ? (s_rf[5]+s_rf[6]+s_rf[7]+s_rf[8]+s_rf[9]) / dlim : 0.f;
    float lf = 0.f, hf = 0.f, lfhf = 0.f;
    if (cond){
      const float df = 0.015625f;
      float acc = 0.f;
      for (int k = 3; k <= 9; ++k){
        float pk2 = 0.5f*(s_pw[2*(k-3)] + s_pw[2*(k-3)+1]);
        acc += (k == 3 || k == 9) ? 0.5f*pk2 : pk2;
      }
      lf = acc * df;
      acc = 0.f;
      for (int k = 10; k <= 25; ++k){
        float pk2 = 0.5f*(s_pw[2*(k-3)] + s_pw[2*(k-3)+1]);
        acc += (k == 10 || k == 25) ? 0.5f*pk2 : pk2;
      }
      hf = acc * df;
      if (hf > 0.f) lfhf = lf / fmaxf(hf, 1e-12f);
    }
    float feats[23] = {s_stash[0], s_stash[1], s_stash[2], s_stash[3],
                       s_stash[4], s_stash[5], s_stash[5]-s_stash[4],
                       s_stash[6], s_stash[7], s_stash[8], s_stash[9],
                       lf, hf, lfhf,
                       s_stash[10], s_stash[11], s_stash[12],
                       rise_t, fall_t,
                       s_stash[13], s_stash[14], s_stash[15], (float)npk};
    float* o = out + (size_t)b * 23;
#pragma unroll
    for (int i = 0; i < 23; ++i){
      float vv = feats[i];
      o[i] = (vv == vv && fabsf(vv) != INFINITY) ? vv : 0.0f;  // nan_to_num
    }
  }
}

extern "C" void kernel_launch(void* const* d_in, const int* in_sizes, int n_in,
                              void* d_out, int out_size, void* d_ws, size_t ws_size,
                              hipStream_t stream){
  const float* x = (const float*)d_in[0];
  float* out = (float*)d_out;
  const int B = in_sizes[0] / TLEN;
  bvp_feat_kernel<<<dim3(B), dim3(NB), 0, stream>>>(x, out);
}